// Round 8
// baseline (1070.860 us; speedup 1.0000x reference)
//
#include <hip/hip_runtime.h>

// NeuralBPDecoder: sparse BP over a 0.1%-dense parity matrix.
// Round 8 = round-6 skeleton (persistent 256x1024 cooperative kernel,
// relaxed-sc1 data path through the coherent Infinity Cache, 8-counter
// relaxed barrier — all PROVEN passing at 438us) + latency-chain fixes:
//   (1) tables padded to static size (rows 40, cols 24), zero-filled,
//       1-based idx + dummy zero line  => fully unrolled gather loops,
//       ONE IF-latency hop per phase instead of 5-6 serial ones;
//   (2) index tables are read-only after build => normal cached loads
//       (each row read by exactly one thread -> L2-resident per XCD).

#define C_NUM 8192
#define V_NUM 16384
#define B_NUM 32
#define ROW_SLOTS 40   // 10 u64; P(row nnz > 40) ~ 6 sigma — never
#define COL_SLOTS 24   // 6 u64;  P(col nnz > 24) ~ 5.5 sigma — never

#define NBLK 256
#define NTHR 1024
#define NTH (NBLK * NTHR)   // 262144 threads

typedef unsigned short u16;
typedef unsigned int u32;
typedef unsigned long long u64;

#define ZERO_WORDS ((C_NUM * 4 + V_NUM * 4 + C_NUM * ROW_SLOTS * 2 + V_NUM * COL_SLOTS * 2) / 4)
#define NBAR 31

__device__ __forceinline__ float agent_ldf(const float* p) {
    return __hip_atomic_load(p, __ATOMIC_RELAXED, __HIP_MEMORY_SCOPE_AGENT);
}
__device__ __forceinline__ void agent_stf(float* p, float v) {
    __hip_atomic_store(p, v, __ATOMIC_RELAXED, __HIP_MEMORY_SCOPE_AGENT);
}
__device__ __forceinline__ void agent_st32(u32* p, u32 v) {
    __hip_atomic_store(p, v, __ATOMIC_RELAXED, __HIP_MEMORY_SCOPE_AGENT);
}
__device__ __forceinline__ void agent_st16(u16* p, u16 v) {
    __hip_atomic_store(p, v, __ATOMIC_RELAXED, __HIP_MEMORY_SCOPE_AGENT);
}

// Relaxed-only grid barrier (round 6, proven): all cross-block data is
// sc1/IF-coherent; __syncthreads + waitcnt drain stores before arrival.
__device__ __forceinline__ void grid_barrier(u32* bars, int id) {
    __syncthreads();
    if (threadIdx.x == 0) {
        u32* base = bars + id * 512;       // 8 counters, 256 B apart
        asm volatile("s_waitcnt vmcnt(0) lgkmcnt(0)" ::: "memory");
        __hip_atomic_fetch_add(base + (blockIdx.x & 7) * 64, 1u,
                               __ATOMIC_RELAXED, __HIP_MEMORY_SCOPE_AGENT);
        u32 sum;
        do {
            sum = 0;
#pragma unroll
            for (int g = 0; g < 8; ++g)
                sum += __hip_atomic_load(base + g * 64,
                                         __ATOMIC_RELAXED, __HIP_MEMORY_SCOPE_AGENT);
            if (sum < (u32)NBLK) __builtin_amdgcn_s_sleep(2);
        } while (sum < (u32)NBLK);
        asm volatile("" ::: "memory");
    }
    __syncthreads();
}

__device__ __forceinline__ float fast_tanh_half(float x) {
    // tanh(x/2) = sign(x) * (1 - e^-|x|) / (1 + e^-|x|)
    float ax = fabsf(x);
    float e = __expf(-ax);
    return copysignf((1.0f - e) / (1.0f + e), x);
}

__global__ __launch_bounds__(NTHR, 1)
void bp_fused(const float* __restrict__ H,      // (C, V)
              const float* __restrict__ synd,   // (B, C)
              const float* __restrict__ llr,    // (B, V)
              const float* __restrict__ w_vc_p,
              const float* __restrict__ w_cv_p,
              const float* __restrict__ damp_p,
              int* __restrict__ row_cnt, int* __restrict__ col_cnt,
              u16* __restrict__ row_tab, u16* __restrict__ col_tab,
              float* __restrict__ bel, float* __restrict__ cms,
              u32* __restrict__ bars,
              float* __restrict__ out) {        // (B, V)
    const int tid = blockIdx.x * NTHR + threadIdx.x;

    // ---- P0: zero counters+tables (contiguous span) + dummy lines + init ----
    {
        u32* zp = (u32*)row_cnt;   // row_cnt,col_cnt,row_tab,col_tab contiguous
        for (int t = tid; t < ZERO_WORDS; t += NTH) agent_st32(&zp[t], 0u);
        if (tid < 32) agent_stf(&bel[tid], 0.0f);          // entity-0 dummy
        else if (tid < 64) agent_stf(&cms[tid - 32], 0.0f);
    }
    float llr_r[2], bel_r[2];
#pragma unroll
    for (int r = 0; r < 2; ++r) {
        int i = tid + r * NTH;          // V_NUM*B_NUM == 2*NTH
        int b = i & 31, v = i >> 5;
        float x = llr[b * V_NUM + v];
        llr_r[r] = x; bel_r[r] = x;
        agent_stf(&bel[i + 32], x);     // (v+1)*32+b == i+32
    }
    float ss_r;
    {
        int b = tid & 31, c = tid >> 5; // C_NUM*B_NUM == NTH
        ss_r = 1.0f - 2.0f * synd[b * C_NUM + c];
    }
    grid_barrier(bars, 0);

    // ---- P1: build padded 1-based tables from dense H (512MB scan) ----
    {
        const int total4 = C_NUM * V_NUM / 4;   // 64 * 2*NTH exactly
        const float4* Hv = (const float4*)H;
        for (int t = tid; t < total4; t += 2 * NTH) {
            float4 h0 = Hv[t];
            float4 h1 = Hv[t + NTH];
#pragma unroll
            for (int half = 0; half < 2; ++half) {
                float4 hv = half ? h1 : h0;
                int base = (half ? (t + NTH) : t) * 4;
                float vals[4] = {hv.x, hv.y, hv.z, hv.w};
#pragma unroll
                for (int k = 0; k < 4; ++k) {
                    if (vals[k] != 0.0f) {
                        int ee = base + k;
                        int c = ee >> 14;            // V = 2^14
                        int v = ee & (V_NUM - 1);
                        int rs = atomicAdd(&row_cnt[c], 1);
                        if (rs < ROW_SLOTS)
                            agent_st16(&row_tab[c * ROW_SLOTS + rs], (u16)(v + 1));
                        int cs = atomicAdd(&col_cnt[v], 1);
                        if (cs < COL_SLOTS)
                            agent_st16(&col_tab[v * COL_SLOTS + cs], (u16)(c + 1));
                    }
                }
            }
        }
    }
    grid_barrier(bars, 1);

    const float wvc = w_vc_p[0];
    const float wcv = w_cv_p[0];
    const float d   = damp_p[0];
    const int b  = tid & 31;
    const int c0 = tid >> 5;

    // ---- P2: 15 BP iterations; static unrolled gathers, pads hit dummy 0 ----
    int barid = 2;
    for (int it = 0; it < 15; ++it) {
        // v->c : cms[c] = ss * tanh(0.5*wvc * sum bel[row]) ; 1 item/thread
        {
            const u64* rt = (const u64*)(row_tab + (size_t)c0 * ROW_SLOTS);
            u64 w[10];
#pragma unroll
            for (int p = 0; p < 10; ++p) w[p] = rt[p];   // normal loads, L2-hot
            float sum = 0.0f;
#pragma unroll
            for (int p = 0; p < 10; ++p) {
                sum += agent_ldf(&bel[(int)(w[p] & 0xFFFFu) * 32 + b]);
                sum += agent_ldf(&bel[(int)((w[p] >> 16) & 0xFFFFu) * 32 + b]);
                sum += agent_ldf(&bel[(int)((w[p] >> 32) & 0xFFFFu) * 32 + b]);
                sum += agent_ldf(&bel[(int)(w[p] >> 48) * 32 + b]);
            }
            agent_stf(&cms[tid + 32], ss_r * fast_tanh_half(wvc * sum));
        }
        grid_barrier(bars, barid++);

        // c->v : bel = d*bel + (1-d)*(llr + wcv*sum cms[col]) ; 2 items/thread
        bool last = (it == 14);
#pragma unroll
        for (int r = 0; r < 2; ++r) {
            int i = tid + r * NTH;
            int v = i >> 5;
            const u64* ct = (const u64*)(col_tab + (size_t)v * COL_SLOTS);
            u64 w[6];
#pragma unroll
            for (int p = 0; p < 6; ++p) w[p] = ct[p];
            float sum = 0.0f;
#pragma unroll
            for (int p = 0; p < 6; ++p) {
                sum += agent_ldf(&cms[(int)(w[p] & 0xFFFFu) * 32 + b]);
                sum += agent_ldf(&cms[(int)((w[p] >> 16) & 0xFFFFu) * 32 + b]);
                sum += agent_ldf(&cms[(int)((w[p] >> 32) & 0xFFFFu) * 32 + b]);
                sum += agent_ldf(&cms[(int)(w[p] >> 48) * 32 + b]);
            }
            float nb = d * bel_r[r] + (1.0f - d) * (llr_r[r] + wcv * sum);
            bel_r[r] = nb;
            if (!last) agent_stf(&bel[i + 32], nb);
            else       out[b * V_NUM + v] = 1.0f / (1.0f + __expf(nb));
        }
        if (!last) grid_barrier(bars, barid++);
    }
}

extern "C" void kernel_launch(void* const* d_in, const int* in_sizes, int n_in,
                              void* d_out, int out_size, void* d_ws, size_t ws_size,
                              hipStream_t stream) {
    const float* synd = (const float*)d_in[0];   // (B, C)
    const float* H    = (const float*)d_in[1];   // (C, V)
    const float* llr  = (const float*)d_in[2];   // (B, V)
    const float* w_vc = (const float*)d_in[3];
    const float* w_cv = (const float*)d_in[4];
    const float* damp = (const float*)d_in[5];
    float* out = (float*)d_out;

    // ws layout: counters+tables CONTIGUOUS at ws start (kernel zero-fills;
    // poison-fill traffic evicts these lines from every L2 before we run).
    char* ws = (char*)d_ws;
    size_t off = 0;
    int* row_cnt = (int*)(ws + off); off += (size_t)C_NUM * 4;               // 32 KB
    int* col_cnt = (int*)(ws + off); off += (size_t)V_NUM * 4;               // 64 KB
    u16* row_tab = (u16*)(ws + off); off += (size_t)C_NUM * ROW_SLOTS * 2;   // 640 KB
    u16* col_tab = (u16*)(ws + off); off += (size_t)V_NUM * COL_SLOTS * 2;   // 768 KB
    float* bel = (float*)(ws + off); off += (size_t)(V_NUM + 1) * 32 * 4;    // 2 MB
    float* cms = (float*)(ws + off); off += (size_t)(C_NUM + 1) * 32 * 4;    // 1 MB
    u32* bars  = (u32*)(ws + off); off += (size_t)NBAR * 512 * 4;            // 62 KB

    // Only the barrier counters need host-side zeroing (ws arrives 0xAA)
    hipMemsetAsync(bars, 0, (size_t)NBAR * 512 * 4, stream);

    void* args[] = {
        (void*)&H, (void*)&synd, (void*)&llr,
        (void*)&w_vc, (void*)&w_cv, (void*)&damp,
        (void*)&row_cnt, (void*)&col_cnt, (void*)&row_tab, (void*)&col_tab,
        (void*)&bel, (void*)&cms, (void*)&bars, (void*)&out
    };
    hipLaunchCooperativeKernel((const void*)bp_fused,
                               dim3(NBLK), dim3(NTHR), args, 0, stream);
}

// Round 9
// 1030.713 us; speedup vs baseline: 1.0390x; 1.0390x over previous
//
#include <hip/hip_runtime.h>

// NeuralBPDecoder: sparse BP over a 0.1%-dense parity matrix.
// Round 9 = round-6/8 persistent skeleton (256x1024 cooperative, relaxed-sc1
// data path via coherent Infinity Cache) + two same-line-serialization fixes:
//   (1) distributed pad indices (hashed valid entities) + cndmask masking
//       at accumulate => static one-IF-hop unrolled gathers WITHOUT the
//       r8 dummy-line hotspot (+3us/phase) and WITHOUT the r6 serial chain;
//   (2) zero-RMW epoch barrier: block k STOREs epoch to flags[k]; wave 0
//       polls all 256 flags lane-parallel (sc1) + 64-lane ballot. Removes
//       the 32-deep same-line fetch_add serialization (~5-8us/barrier).

#define C_NUM 8192
#define V_NUM 16384
#define B_NUM 32
#define ROW_SLOTS 40   // 10 u64; P(row nnz > 40) ~ 6 sigma
#define COL_SLOTS 24   // 6 u64;  P(col nnz > 24) ~ 5.5 sigma

#define NBLK 256
#define NTHR 1024
#define NTH (NBLK * NTHR)   // 262144 threads

typedef unsigned short u16;
typedef unsigned int u32;
typedef unsigned long long u64;

__device__ __forceinline__ float agent_ldf(const float* p) {
    return __hip_atomic_load(p, __ATOMIC_RELAXED, __HIP_MEMORY_SCOPE_AGENT);
}
__device__ __forceinline__ void agent_stf(float* p, float v) {
    __hip_atomic_store(p, v, __ATOMIC_RELAXED, __HIP_MEMORY_SCOPE_AGENT);
}
__device__ __forceinline__ u32 agent_ld32(const u32* p) {
    return __hip_atomic_load(p, __ATOMIC_RELAXED, __HIP_MEMORY_SCOPE_AGENT);
}
__device__ __forceinline__ void agent_st32(u32* p, u32 v) {
    __hip_atomic_store(p, v, __ATOMIC_RELAXED, __HIP_MEMORY_SCOPE_AGENT);
}
__device__ __forceinline__ int agent_ldi(const int* p) {
    return __hip_atomic_load(p, __ATOMIC_RELAXED, __HIP_MEMORY_SCOPE_AGENT);
}
__device__ __forceinline__ void agent_st16(u16* p, u16 v) {
    __hip_atomic_store(p, v, __ATOMIC_RELAXED, __HIP_MEMORY_SCOPE_AGENT);
}

// Epoch barrier, zero RMW. Sound: all cross-block data is sc1 (IF-coherent);
// each wave's vmcnt drains before s_barrier (compiler-enforced), so when
// thread 0 stores the epoch every store of this block is at the coherence
// point. Monotonic epochs -> no counter reset, one 1KB flags array.
__device__ __forceinline__ void grid_barrier(u32* flags, u32 ep) {
    __syncthreads();
    if (threadIdx.x < 64) {
        if (threadIdx.x == 0) {
            asm volatile("s_waitcnt vmcnt(0) lgkmcnt(0)" ::: "memory");
            agent_st32(&flags[blockIdx.x], ep);
        }
        const int base = threadIdx.x * 4;   // lane i covers blocks 4i..4i+3
        for (;;) {
            u32 f0 = agent_ld32(&flags[base + 0]);
            u32 f1 = agent_ld32(&flags[base + 1]);
            u32 f2 = agent_ld32(&flags[base + 2]);
            u32 f3 = agent_ld32(&flags[base + 3]);
            bool ok = (f0 >= ep) & (f1 >= ep) & (f2 >= ep) & (f3 >= ep);
            if (__ballot(ok) == ~0ull) break;
            __builtin_amdgcn_s_sleep(2);
        }
        asm volatile("" ::: "memory");
    }
    __syncthreads();
}

__device__ __forceinline__ float fast_tanh_half(float x) {
    // tanh(x/2) = sign(x) * (1 - e^-|x|) / (1 + e^-|x|)
    float ax = fabsf(x);
    float e = __expf(-ax);
    return copysignf((1.0f - e) / (1.0f + e), x);
}

__global__ __launch_bounds__(NTHR, 4)
void bp_fused(const float* __restrict__ H,      // (C, V)
              const float* __restrict__ synd,   // (B, C)
              const float* __restrict__ llr,    // (B, V)
              const float* __restrict__ w_vc_p,
              const float* __restrict__ w_cv_p,
              const float* __restrict__ damp_p,
              int* __restrict__ row_cnt, int* __restrict__ col_cnt,
              u16* __restrict__ row_tab, u16* __restrict__ col_tab,
              float* __restrict__ bel, float* __restrict__ cms,
              u32* __restrict__ flags,
              float* __restrict__ out) {        // (B, V)
    const int tid = blockIdx.x * NTHR + threadIdx.x;
    u32 ep = 1;

    // ---- P0: zero counters + init state (entity indices are 1-based) ----
    {
        u32* zp = (u32*)row_cnt;   // row_cnt,col_cnt contiguous
        for (int t = tid; t < (C_NUM + V_NUM); t += NTH) agent_st32(&zp[t], 0u);
    }
    float llr_r[2], bel_r[2];
#pragma unroll
    for (int r = 0; r < 2; ++r) {
        int i = tid + r * NTH;          // V_NUM*B_NUM == 2*NTH ; i = v*32+b
        int b = i & 31, v = i >> 5;
        float x = llr[b * V_NUM + v];
        llr_r[r] = x; bel_r[r] = x;
        agent_stf(&bel[i + 32], x);     // entity v+1
    }
    float ss_r;
    {
        int b = tid & 31, c = tid >> 5; // C_NUM*B_NUM == NTH
        ss_r = 1.0f - 2.0f * synd[b * C_NUM + c];
    }
    grid_barrier(flags, ep++);

    // ---- P1: build 1-based tables from dense H (512MB scan) ----
    {
        const int total4 = C_NUM * V_NUM / 4;   // 64 * 2*NTH exactly
        const float4* Hv = (const float4*)H;
        for (int t = tid; t < total4; t += 2 * NTH) {
            float4 h0 = Hv[t];
            float4 h1 = Hv[t + NTH];
#pragma unroll
            for (int half = 0; half < 2; ++half) {
                float4 hv = half ? h1 : h0;
                int base = (half ? (t + NTH) : t) * 4;
                float vals[4] = {hv.x, hv.y, hv.z, hv.w};
#pragma unroll
                for (int k = 0; k < 4; ++k) {
                    if (vals[k] != 0.0f) {
                        int ee = base + k;
                        int c = ee >> 14;            // V = 2^14
                        int v = ee & (V_NUM - 1);
                        int rs = atomicAdd(&row_cnt[c], 1);
                        if (rs < ROW_SLOTS)
                            agent_st16(&row_tab[c * ROW_SLOTS + rs], (u16)(v + 1));
                        int cs = atomicAdd(&col_cnt[v], 1);
                        if (cs < COL_SLOTS)
                            agent_st16(&col_tab[v * COL_SLOTS + cs], (u16)(c + 1));
                    }
                }
            }
        }
    }
    grid_barrier(flags, ep++);

    // ---- P1b: fill tail slots with DISTRIBUTED valid pad indices ----
    // (masked out at accumulate; spreading kills the r8 one-line hotspot)
    if (tid < C_NUM) {
        int c = tid;
        int n = agent_ldi(&row_cnt[c]); n = n > ROW_SLOTS ? ROW_SLOTS : n;
        for (int k = n; k < ROW_SLOTS; ++k)
            agent_st16(&row_tab[c * ROW_SLOTS + k],
                       (u16)((((c * 97) + (k * 131)) & (V_NUM - 1)) + 1));
    } else if (tid < C_NUM + V_NUM) {
        int v = tid - C_NUM;
        int n = agent_ldi(&col_cnt[v]); n = n > COL_SLOTS ? COL_SLOTS : n;
        for (int k = n; k < COL_SLOTS; ++k)
            agent_st16(&col_tab[v * COL_SLOTS + k],
                       (u16)((((v * 89) + (k * 61)) & (C_NUM - 1)) + 1));
    }
    // phase constants
    const float wvc = w_vc_p[0];
    const float wcv = w_cv_p[0];
    const float d   = damp_p[0];
    const int b  = tid & 31;
    const int c0 = tid >> 5;
    int n_row;
    {
        int n = agent_ldi(&row_cnt[c0]);
        n_row = n > ROW_SLOTS ? ROW_SLOTS : n;
    }
    int n_col[2];
#pragma unroll
    for (int r = 0; r < 2; ++r) {
        int n = agent_ldi(&col_cnt[(tid + r * NTH) >> 5]);
        n_col[r] = n > COL_SLOTS ? COL_SLOTS : n;
    }
    grid_barrier(flags, ep++);

    // ---- P2: 15 BP iterations; static unrolled masked gathers ----
    for (int it = 0; it < 15; ++it) {
        // v->c : cms[c] = ss * tanh(0.5*wvc * sum bel[row]) ; 1 item/thread
        {
            const u64* rt = (const u64*)(row_tab + (size_t)c0 * ROW_SLOTS);
            float sum = 0.0f;
#pragma unroll
            for (int p = 0; p < ROW_SLOTS / 4; ++p) {
                u64 q = rt[p];                       // L2-hot, read-only
                float v0 = agent_ldf(&bel[(int)(q & 0xFFFFu) * 32 + b]);
                float v1 = agent_ldf(&bel[(int)((q >> 16) & 0xFFFFu) * 32 + b]);
                float v2 = agent_ldf(&bel[(int)((q >> 32) & 0xFFFFu) * 32 + b]);
                float v3 = agent_ldf(&bel[(int)(q >> 48) * 32 + b]);
                int j = p * 4;
                sum += (j     < n_row) ? v0 : 0.0f;  // v_cndmask, no branch
                sum += (j + 1 < n_row) ? v1 : 0.0f;
                sum += (j + 2 < n_row) ? v2 : 0.0f;
                sum += (j + 3 < n_row) ? v3 : 0.0f;
            }
            agent_stf(&cms[tid + 32], ss_r * fast_tanh_half(wvc * sum));
        }
        grid_barrier(flags, ep++);

        // c->v : bel = d*bel + (1-d)*(llr + wcv*sum cms[col]) ; 2 items/thread
        bool last = (it == 14);
#pragma unroll
        for (int r = 0; r < 2; ++r) {
            int i = tid + r * NTH;
            int v = i >> 5;
            const u64* ct = (const u64*)(col_tab + (size_t)v * COL_SLOTS);
            float sum = 0.0f;
#pragma unroll
            for (int p = 0; p < COL_SLOTS / 4; ++p) {
                u64 q = ct[p];
                float v0 = agent_ldf(&cms[(int)(q & 0xFFFFu) * 32 + b]);
                float v1 = agent_ldf(&cms[(int)((q >> 16) & 0xFFFFu) * 32 + b]);
                float v2 = agent_ldf(&cms[(int)((q >> 32) & 0xFFFFu) * 32 + b]);
                float v3 = agent_ldf(&cms[(int)(q >> 48) * 32 + b]);
                int j = p * 4;
                sum += (j     < n_col[r]) ? v0 : 0.0f;
                sum += (j + 1 < n_col[r]) ? v1 : 0.0f;
                sum += (j + 2 < n_col[r]) ? v2 : 0.0f;
                sum += (j + 3 < n_col[r]) ? v3 : 0.0f;
            }
            float nb = d * bel_r[r] + (1.0f - d) * (llr_r[r] + wcv * sum);
            bel_r[r] = nb;
            if (!last) agent_stf(&bel[i + 32], nb);
            else       out[b * V_NUM + v] = 1.0f / (1.0f + __expf(nb));
        }
        if (!last) grid_barrier(flags, ep++);
    }
}

extern "C" void kernel_launch(void* const* d_in, const int* in_sizes, int n_in,
                              void* d_out, int out_size, void* d_ws, size_t ws_size,
                              hipStream_t stream) {
    const float* synd = (const float*)d_in[0];   // (B, C)
    const float* H    = (const float*)d_in[1];   // (C, V)
    const float* llr  = (const float*)d_in[2];   // (B, V)
    const float* w_vc = (const float*)d_in[3];
    const float* w_cv = (const float*)d_in[4];
    const float* damp = (const float*)d_in[5];
    float* out = (float*)d_out;

    char* ws = (char*)d_ws;
    size_t off = 0;
    int* row_cnt = (int*)(ws + off); off += (size_t)C_NUM * 4;               // 32 KB
    int* col_cnt = (int*)(ws + off); off += (size_t)V_NUM * 4;               // 64 KB
    u16* row_tab = (u16*)(ws + off); off += (size_t)C_NUM * ROW_SLOTS * 2;   // 640 KB
    u16* col_tab = (u16*)(ws + off); off += (size_t)V_NUM * COL_SLOTS * 2;   // 768 KB
    float* bel = (float*)(ws + off); off += (size_t)(V_NUM + 1) * 32 * 4;    // 2 MB
    float* cms = (float*)(ws + off); off += (size_t)(C_NUM + 1) * 32 * 4;    // 1 MB
    u32* flags = (u32*)(ws + off); off += (size_t)NBLK * 4;                  // 1 KB

    // Only the epoch flags need host-side zeroing (ws arrives 0xAA)
    hipMemsetAsync(flags, 0, (size_t)NBLK * 4, stream);

    void* args[] = {
        (void*)&H, (void*)&synd, (void*)&llr,
        (void*)&w_vc, (void*)&w_cv, (void*)&damp,
        (void*)&row_cnt, (void*)&col_cnt, (void*)&row_tab, (void*)&col_tab,
        (void*)&bel, (void*)&cms, (void*)&flags, (void*)&out
    };
    hipLaunchCooperativeKernel((const void*)bp_fused,
                               dim3(NBLK), dim3(NTHR), args, 0, stream);
}